// Round 4
// baseline (584.130 us; speedup 1.0000x reference)
//
#include <hip/hip_runtime.h>

typedef unsigned short u16;
typedef __bf16 bf16_t;
typedef __bf16 bf16x8 __attribute__((ext_vector_type(8)));
typedef float f32x4 __attribute__((ext_vector_type(4)));
typedef unsigned short u16x8 __attribute__((ext_vector_type(8)));
typedef unsigned short u16x4 __attribute__((ext_vector_type(4)));

#define S_LEN 2048
#define NHEAD 16
#define HD 128
#define HID 2048
#define QKV_N 6144

__device__ __forceinline__ float b2f(u16 u) {
  union { unsigned int i; float f; } x; x.i = ((unsigned int)u) << 16; return x.f;
}
__device__ __forceinline__ u16 f2b(float f) {
  bf16_t h = (bf16_t)f;
  return __builtin_bit_cast(unsigned short, h);
}

// ---------------- dtype sniffer: 1 if fp32, 0 if bf16 ----------------
__global__ void detect_dtype_k(const void* __restrict__ x, int* __restrict__ flag) {
  __shared__ int cnt;
  if (threadIdx.x == 0) cnt = 0;
  __syncthreads();
  const u16* xu = (const u16*)x;
  int sane = 0;
  for (int i = threadIdx.x; i < 8192; i += 256) {
    int e = (xu[i] >> 7) & 0xFF;
    if (e == 0 || (e > 100 && e < 140)) sane++;
  }
  atomicAdd(&cnt, sane);
  __syncthreads();
  if (threadIdx.x == 0) *flag = (cnt < 7373) ? 1 : 0;  // <90% sane => fp32
}

// ---------------- convert input (fp32|bf16) -> bf16 ----------------
__global__ __launch_bounds__(256) void convert_any_k(const void* __restrict__ in, u16* __restrict__ out,
                                                     const int* __restrict__ flag) {
  int i = (blockIdx.x * 256 + threadIdx.x) * 4;
  if (*flag) {
    const float4 v = *(const float4*)((const float*)in + i);
    u16x4 o = {f2b(v.x), f2b(v.y), f2b(v.z), f2b(v.w)};
    *(u16x4*)(out + i) = o;
  } else {
    *(u16x4*)(out + i) = *(const u16x4*)((const u16*)in + i);
  }
}

// ---------------- transpose [R][C] -> [C][R], (fp32|bf16) in -> bf16 out ----------------
__global__ __launch_bounds__(256) void transpose_any(const void* __restrict__ in,
                                                     u16* __restrict__ out, int R, int C,
                                                     const int* __restrict__ flag) {
  __shared__ u16 t[64][65];
  bool isf = (*flag != 0);
  int tid = threadIdx.x;
  int r0 = blockIdx.y * 64, c0 = blockIdx.x * 64;
#pragma unroll
  for (int p = 0; p < 16; ++p) {
    int e = p * 256 + tid;
    int r = e >> 6, c = e & 63;
    size_t idx = (size_t)(r0 + r) * C + (c0 + c);
    t[r][c] = isf ? f2b(((const float*)in)[idx]) : ((const u16*)in)[idx];
  }
  __syncthreads();
#pragma unroll
  for (int p = 0; p < 16; ++p) {
    int e = p * 256 + tid;
    int r = e >> 6, c = e & 63;
    out[(size_t)(c0 + r) * R + (r0 + c)] = t[c][r];
  }
}

// ---------------- RoPE cos/sin table: tab[s*128 + d]=cos, +64=sin ----------------
__global__ void rope_table_k(float* __restrict__ tab) {
  int i = blockIdx.x * 256 + threadIdx.x;  // 131072 = 2048*64
  int s = i >> 6, d = i & 63;
  float inv = expf(-(float)d * (9.210340371976184f / 64.0f));  // 10000^(-d/64)
  float ang = (float)s * inv;
  tab[s * 128 + d] = cosf(ang);
  tab[s * 128 + 64 + d] = sinf(ang);
}

// ---------------- relative bias: bias[h][dist], dist in [0,2048) ----------------
__global__ void build_bias_k(const void* __restrict__ table, float* __restrict__ bias,
                             const int* __restrict__ flag) {
  int i = blockIdx.x * 256 + threadIdx.x;  // 32768 = 16*2048
  int h = i >> 11, dist = i & 2047;
  int bucket;
  if (dist < 16) bucket = dist;
  else {
    // mirror ref fp32 op order: log(n/16) / log(8) * 16, trunc, +16
    int lb = (int)(logf((float)dist * 0.0625f) / 2.0794415f * 16.0f) + 16;
    bucket = lb < 31 ? lb : 31;
  }
  int ti = bucket * NHEAD + h;
  float tv = (*flag) ? ((const float*)table)[ti] : b2f(((const u16*)table)[ti]);
  bias[h * 2048 + dist] = tv;
}

// ---------------- GEMM: C[M][N] = A[M][K] * B[N][K]^T (bf16 in, fp32 acc) ----------------
// F32OUT=false: C is bf16 (u16). F32OUT=true: C is fp32 (float).
template <bool F32OUT>
__global__ __launch_bounds__(256) void gemm_bt(const u16* __restrict__ A, const u16* __restrict__ B,
                                               void* __restrict__ Cv, int M, int N, int K) {
  __shared__ u16 As[128][40];  // 32 cols + 8 pad
  __shared__ u16 Bs[128][40];
  int tid = threadIdx.x;
  int lane = tid & 63, wv = tid >> 6;
  int wm = wv & 1, wn = wv >> 1;
  int lane16 = lane & 15, quad = lane >> 4;
  int m0 = blockIdx.y * 128, n0 = blockIdx.x * 128;
  int srow = tid >> 2, scol = (tid & 3) * 8;
  const u16* pA = A + (size_t)(m0 + srow) * K + scol;
  const u16* pB = B + (size_t)(n0 + srow) * K + scol;

  f32x4 zero4 = {0.f, 0.f, 0.f, 0.f};
  f32x4 acc[4][4];
#pragma unroll
  for (int i = 0; i < 4; ++i)
#pragma unroll
    for (int j = 0; j < 4; ++j) acc[i][j] = zero4;

  int nk = K >> 5;
  for (int kt = 0; kt < nk; ++kt) {
    __syncthreads();
    u16x8 a0 = *(const u16x8*)(pA);
    u16x8 a1 = *(const u16x8*)(pA + (size_t)64 * K);
    u16x8 b0 = *(const u16x8*)(pB);
    u16x8 b1 = *(const u16x8*)(pB + (size_t)64 * K);
    pA += 32; pB += 32;
    *(u16x8*)&As[srow][scol] = a0;
    *(u16x8*)&As[srow + 64][scol] = a1;
    *(u16x8*)&Bs[srow][scol] = b0;
    *(u16x8*)&Bs[srow + 64][scol] = b1;
    __syncthreads();
    bf16x8 af[4], bfr[4];
#pragma unroll
    for (int i = 0; i < 4; ++i) af[i] = *(const bf16x8*)&As[wm * 64 + i * 16 + lane16][quad * 8];
#pragma unroll
    for (int j = 0; j < 4; ++j) bfr[j] = *(const bf16x8*)&Bs[wn * 64 + j * 16 + lane16][quad * 8];
#pragma unroll
    for (int i = 0; i < 4; ++i)
#pragma unroll
      for (int j = 0; j < 4; ++j)
        acc[i][j] = __builtin_amdgcn_mfma_f32_16x16x32_bf16(af[i], bfr[j], acc[i][j], 0, 0, 0);
  }
  // epilogue: C/D layout col=lane&15, row=quad*4+reg
#pragma unroll
  for (int i = 0; i < 4; ++i)
#pragma unroll
    for (int j = 0; j < 4; ++j)
#pragma unroll
      for (int r = 0; r < 4; ++r) {
        int row = m0 + wm * 64 + i * 16 + quad * 4 + r;
        int col = n0 + wn * 64 + j * 16 + lane16;
        if (F32OUT)
          ((float*)Cv)[(size_t)row * N + col] = acc[i][j][r];
        else
          ((u16*)Cv)[(size_t)row * N + col] = f2b(acc[i][j][r]);
      }
}

// ---------------- reorg: qkv[B,S,6144] -> q,k [bh,S,D] (roped), vT [bh,D,S] ----------------
__global__ __launch_bounds__(256) void reorg_k(const u16* __restrict__ qkv, const float* __restrict__ tab,
                                               u16* __restrict__ q, u16* __restrict__ k,
                                               u16* __restrict__ vT) {
  __shared__ float vt[64][129];
  int tid = threadIdx.x;
  int st = blockIdx.x, bh = blockIdx.y;
  int b = bh >> 4, h = bh & 15;
  int s0 = st * 64;
  const u16* base = qkv + (size_t)(b * S_LEN + s0) * QKV_N + h * HD;
  u16* qo = q + ((size_t)bh * S_LEN + s0) * HD;
  u16* ko = k + ((size_t)bh * S_LEN + s0) * HD;
#pragma unroll
  for (int p = 0; p < 16; ++p) {
    int e = p * 256 + tid;  // 4096 (s,d<64) pairs
    int sl = e >> 6, d = e & 63;
    float c = tab[(s0 + sl) * 128 + d];
    float sn = tab[(s0 + sl) * 128 + 64 + d];
    const u16* rowp = base + (size_t)sl * QKV_N;
    float q1 = b2f(rowp[d]), q2 = b2f(rowp[d + 64]);
    qo[sl * HD + d] = f2b(q1 * c - q2 * sn);
    qo[sl * HD + d + 64] = f2b(q2 * c + q1 * sn);
    float k1 = b2f(rowp[2048 + d]), k2 = b2f(rowp[2048 + d + 64]);
    ko[sl * HD + d] = f2b(k1 * c - k2 * sn);
    ko[sl * HD + d + 64] = f2b(k2 * c + k1 * sn);
  }
  // v transpose through LDS
#pragma unroll
  for (int p = 0; p < 32; ++p) {
    int e = p * 256 + tid;  // 8192
    int sl = e >> 7, d = e & 127;
    vt[sl][d] = b2f(base[(size_t)sl * QKV_N + 4096 + d]);
  }
  __syncthreads();
  u16* vo = vT + (size_t)bh * HD * S_LEN;
#pragma unroll
  for (int p = 0; p < 32; ++p) {
    int e = p * 256 + tid;
    int d = e >> 6, sl = e & 63;
    vo[(size_t)d * S_LEN + s0 + sl] = f2b(vt[sl][d]);
  }
}

// ---------------- flash attention: q,k [bh,S,D], vT [bh,D,S] -> ctx [B,S,2048] ----------------
__global__ __launch_bounds__(256) void attn_k(const u16* __restrict__ q, const u16* __restrict__ k,
                                              const u16* __restrict__ vT, const float* __restrict__ bias,
                                              u16* __restrict__ ctx) {
  __shared__ u16 Ks[64][136];   // 128 data + 8 pad
  __shared__ u16 VTs[128][72];  // 64 data + 8 pad
  __shared__ u16 QP[64][136];   // Q staging, then per-wave P tiles [16][72]
  __shared__ float bias_s[128];
  int tid = threadIdx.x;
  int lane = tid & 63, wq = tid >> 6;
  int lane16 = lane & 15, quad = lane >> 4;
  int qt = blockIdx.x, bh = blockIdx.y;
  int b = bh >> 4, h = bh & 15;
  int q0 = qt * 64;
  const u16* qg = q + ((size_t)bh * S_LEN + q0) * HD;
  const u16* kg = k + (size_t)bh * S_LEN * HD;
  const u16* vg = vT + (size_t)bh * HD * S_LEN;
  const float* biasr = bias + h * 2048;

  {  // stage Q tile 64x128
    int r = tid >> 4, c = (tid & 15) * 8;
#pragma unroll
    for (int p = 0; p < 4; ++p)
      *(u16x8*)&QP[r + p * 16][c] = *(const u16x8*)&qg[(size_t)(r + p * 16) * HD + c];
  }
  __syncthreads();
  bf16x8 qf[4];  // A-frags: m=lane16 (q row), k=quad*8+j
#pragma unroll
  for (int kd = 0; kd < 4; ++kd)
    qf[kd] = *(const bf16x8*)&QP[wq * 16 + lane16][kd * 32 + quad * 8];
  __syncthreads();  // all Q reads done before any wave writes P into QP

  u16* Pw = &QP[0][0] + wq * 1152;  // per-wave [16][72]

  float m_i[4], l_i[4];
  f32x4 zero4 = {0.f, 0.f, 0.f, 0.f};
  f32x4 o[8];
#pragma unroll
  for (int r = 0; r < 4; ++r) { m_i[r] = -1e30f; l_i[r] = 0.f; }
#pragma unroll
  for (int dt = 0; dt < 8; ++dt) o[dt] = zero4;

  const float scale = 0.08838834764831845f;  // 1/sqrt(128)
  int nkt = qt + 1;
  for (int kt = 0; kt < nkt; ++kt) {
    int k0 = kt * 64;
    __syncthreads();
    {  // stage K tile 64x128
      int r = tid >> 4, c = (tid & 15) * 8;
#pragma unroll
      for (int p = 0; p < 4; ++p)
        *(u16x8*)&Ks[r + p * 16][c] = *(const u16x8*)&kg[(size_t)(k0 + r + p * 16) * HD + c];
    }
    {  // stage V^T tile 128x64
      int d = tid >> 3, c = (tid & 7) * 8;
#pragma unroll
      for (int p = 0; p < 4; ++p)
        *(u16x8*)&VTs[d + p * 32][c] = *(const u16x8*)&vg[(size_t)(d + p * 32) * S_LEN + k0 + c];
    }
    if (tid < 128) {
      int dist = q0 - k0 + tid - 64;
      bias_s[tid] = (dist >= 0) ? biasr[dist] : 0.f;
    }
    __syncthreads();

    // S = Q K^T  (4 n-tiles of 16 k-cols each)
    f32x4 sc[4];
#pragma unroll
    for (int j = 0; j < 4; ++j) sc[j] = zero4;
#pragma unroll
    for (int kd = 0; kd < 4; ++kd)
#pragma unroll
      for (int j = 0; j < 4; ++j) {
        bf16x8 kf = *(const bf16x8*)&Ks[j * 16 + lane16][kd * 32 + quad * 8];
        sc[j] = __builtin_amdgcn_mfma_f32_16x16x32_bf16(qf[kd], kf, sc[j], 0, 0, 0);
      }

    // scale + bias + causal mask (C layout: row=quad*4+r, col=j*16+lane16)
    int qrel = wq * 16 + quad * 4;
#pragma unroll
    for (int j = 0; j < 4; ++j) {
      int krel = j * 16 + lane16;
#pragma unroll
      for (int r = 0; r < 4; ++r) {
        bool valid = (q0 + qrel + r) >= (k0 + krel);
        float sv = sc[j][r] * scale + bias_s[64 + (qrel + r) - krel];
        sc[j][r] = valid ? sv : -1e30f;
      }
    }
    // online softmax: row spans 16 lanes (quad) x 4 j-tiles
    float mx[4];
#pragma unroll
    for (int r = 0; r < 4; ++r)
      mx[r] = fmaxf(fmaxf(sc[0][r], sc[1][r]), fmaxf(sc[2][r], sc[3][r]));
#pragma unroll
    for (int xm = 1; xm < 16; xm <<= 1)
#pragma unroll
      for (int r = 0; r < 4; ++r) mx[r] = fmaxf(mx[r], __shfl_xor(mx[r], xm));
    float alpha[4];
#pragma unroll
    for (int r = 0; r < 4; ++r) {
      float mn = fmaxf(m_i[r], mx[r]);
      alpha[r] = __expf(m_i[r] - mn);
      m_i[r] = mn;
    }
#pragma unroll
    for (int j = 0; j < 4; ++j)
#pragma unroll
      for (int r = 0; r < 4; ++r) sc[j][r] = __expf(sc[j][r] - m_i[r]);
    float rs[4];
#pragma unroll
    for (int r = 0; r < 4; ++r) rs[r] = (sc[0][r] + sc[1][r]) + (sc[2][r] + sc[3][r]);
#pragma unroll
    for (int xm = 1; xm < 16; xm <<= 1)
#pragma unroll
      for (int r = 0; r < 4; ++r) rs[r] += __shfl_xor(rs[r], xm);
#pragma unroll
    for (int r = 0; r < 4; ++r) l_i[r] = l_i[r] * alpha[r] + rs[r];
#pragma unroll
    for (int dt = 0; dt < 8; ++dt)
#pragma unroll
      for (int r = 0; r < 4; ++r) o[dt][r] *= alpha[r];

    // P: C layout -> A layout via LDS (per-wave region)
#pragma unroll
    for (int j = 0; j < 4; ++j)
#pragma unroll
      for (int r = 0; r < 4; ++r)
        Pw[(quad * 4 + r) * 72 + j * 16 + lane16] = f2b(sc[j][r]);
    __syncthreads();

    // O += P V   (A=P[16x64], B=V[64x128] via VTs rows=d)
#pragma unroll
    for (int ks = 0; ks < 2; ++ks) {
      bf16x8 pf = *(const bf16x8*)&Pw[lane16 * 72 + ks * 32 + quad * 8];
#pragma unroll
      for (int dt = 0; dt < 8; ++dt) {
        bf16x8 vf = *(const bf16x8*)&VTs[dt * 16 + lane16][ks * 32 + quad * 8];
        o[dt] = __builtin_amdgcn_mfma_f32_16x16x32_bf16(pf, vf, o[dt], 0, 0, 0);
      }
    }
  }
  // epilogue: ctx[b][s][h*128+d]
#pragma unroll
  for (int r = 0; r < 4; ++r) {
    float invl = 1.0f / l_i[r];
    int srow = q0 + wq * 16 + quad * 4 + r;
    u16* orow = ctx + ((size_t)b * S_LEN + srow) * HID + h * HD;
#pragma unroll
    for (int dt = 0; dt < 8; ++dt)
      orow[dt * 16 + lane16] = f2b(o[dt][r] * invl);
  }
}

extern "C" void kernel_launch(void* const* d_in, const int* in_sizes, int n_in,
                              void* d_out, int out_size, void* d_ws, size_t ws_size,
                              hipStream_t stream) {
  const void* x       = d_in[0];  // [2,2048,2048]   fp32 (sniffed; bf16 also handled)
  const void* qkv_w   = d_in[1];  // [2048,6144]
  const void* dense_w = d_in[2];  // [2048,2048]
  const void* rtable  = d_in[3];  // [32,16]
  char* ws = (char*)d_ws;

  // Compact layout with overlays (total 118,620,416 B = 113.1 MiB):
  int*   flag  = (int*)(ws);                 // @0         256 B
  float* bias  = (float*)(ws + 256);         // @256       131,072
  float* tab   = (float*)(ws + 131328);      // @131,328   1,048,576
  u16*   wdT   = (u16*)(ws + 1179904);       // @1,179,904 8,388,608   (live until gemm2)
  u16*   vT    = (u16*)(ws + 9568512);       // @9.57M     16,777,216
  u16*   x_bf  = (u16*)(ws + 26345728);      // @26.3M     16,777,216  (dead after gemm1)
  u16*   qA    = x_bf;                       //   -> reused by reorg for roped Q
  u16*   wqkvT = (u16*)(ws + 43122944);      // @43.1M     25,165,824  (dead after gemm1)
  u16*   kA    = wqkvT;                      //   -> reused by reorg for roped K
  u16*   qkv   = (u16*)(ws + 68288768);      // @68.3M     50,331,648  (dead after reorg)
  u16*   ctx   = qkv;                        //   -> reused by attn for context

  detect_dtype_k<<<1, 256, 0, stream>>>(x, flag);
  convert_any_k<<<8192, 256, 0, stream>>>(x, x_bf, flag);   // 8,388,608 elems
  transpose_any<<<dim3(96, 32), 256, 0, stream>>>(qkv_w, wqkvT, 2048, 6144, flag);
  transpose_any<<<dim3(32, 32), 256, 0, stream>>>(dense_w, wdT, 2048, 2048, flag);
  rope_table_k<<<512, 256, 0, stream>>>(tab);
  build_bias_k<<<128, 256, 0, stream>>>(rtable, bias, flag);
  gemm_bt<false><<<dim3(48, 32), 256, 0, stream>>>(x_bf, wqkvT, qkv, 4096, 6144, 2048);
  reorg_k<<<dim3(32, 32), 256, 0, stream>>>(qkv, tab, qA, kA, vT);
  attn_k<<<dim3(32, 32), 256, 0, stream>>>(qA, kA, vT, bias, ctx);
  gemm_bt<true><<<dim3(16, 32), 256, 0, stream>>>(ctx, wdT, d_out, 4096, 2048, 2048);
}

// Round 5
// 470.492 us; speedup vs baseline: 1.2415x; 1.2415x over previous
//
#include <hip/hip_runtime.h>

typedef unsigned short u16;
typedef __bf16 bf16_t;
typedef __bf16 bf16x8 __attribute__((ext_vector_type(8)));
typedef float f32x4 __attribute__((ext_vector_type(4)));
typedef unsigned short u16x8 __attribute__((ext_vector_type(8)));
typedef unsigned short u16x4 __attribute__((ext_vector_type(4)));

#define S_LEN 2048
#define NHEAD 16
#define HD 128
#define HID 2048
#define QKV_N 6144

__device__ __forceinline__ float b2f(u16 u) {
  union { unsigned int i; float f; } x; x.i = ((unsigned int)u) << 16; return x.f;
}
__device__ __forceinline__ u16 f2b(float f) {
  bf16_t h = (bf16_t)f;
  return __builtin_bit_cast(unsigned short, h);
}

// async global->LDS, 16B per lane. lds dest must be wave-uniform; data lands at
// dest + lane*16. Drained by the vmcnt(0) implicit in __syncthreads().
__device__ __forceinline__ void gl_lds16(const u16* g, u16* l) {
  __builtin_amdgcn_global_load_lds(
      (const __attribute__((address_space(1))) unsigned int*)g,
      (__attribute__((address_space(3))) unsigned int*)l, 16, 0, 0);
}

// ---------------- dtype sniffer: 1 if fp32, 0 if bf16 ----------------
__global__ void detect_dtype_k(const void* __restrict__ x, int* __restrict__ flag) {
  __shared__ int cnt;
  if (threadIdx.x == 0) cnt = 0;
  __syncthreads();
  const u16* xu = (const u16*)x;
  int sane = 0;
  for (int i = threadIdx.x; i < 8192; i += 256) {
    int e = (xu[i] >> 7) & 0xFF;
    if (e == 0 || (e > 100 && e < 140)) sane++;
  }
  atomicAdd(&cnt, sane);
  __syncthreads();
  if (threadIdx.x == 0) *flag = (cnt < 7373) ? 1 : 0;
}

// ---------------- convert input (fp32|bf16) -> bf16 ----------------
__global__ __launch_bounds__(256) void convert_any_k(const void* __restrict__ in, u16* __restrict__ out,
                                                     const int* __restrict__ flag) {
  int i = (blockIdx.x * 256 + threadIdx.x) * 4;
  if (*flag) {
    const float4 v = *(const float4*)((const float*)in + i);
    u16x4 o = {f2b(v.x), f2b(v.y), f2b(v.z), f2b(v.w)};
    *(u16x4*)(out + i) = o;
  } else {
    *(u16x4*)(out + i) = *(const u16x4*)((const u16*)in + i);
  }
}

// ---------------- transpose [R][C] -> [C][R], (fp32|bf16) in -> bf16 out ----------------
__global__ __launch_bounds__(256) void transpose_any(const void* __restrict__ in,
                                                     u16* __restrict__ out, int R, int C,
                                                     const int* __restrict__ flag) {
  __shared__ u16 t[64][65];
  bool isf = (*flag != 0);
  int tid = threadIdx.x;
  int r0 = blockIdx.y * 64, c0 = blockIdx.x * 64;
#pragma unroll
  for (int p = 0; p < 16; ++p) {
    int e = p * 256 + tid;
    int r = e >> 6, c = e & 63;
    size_t idx = (size_t)(r0 + r) * C + (c0 + c);
    t[r][c] = isf ? f2b(((const float*)in)[idx]) : ((const u16*)in)[idx];
  }
  __syncthreads();
#pragma unroll
  for (int p = 0; p < 16; ++p) {
    int e = p * 256 + tid;
    int r = e >> 6, c = e & 63;
    out[(size_t)(c0 + r) * R + (r0 + c)] = t[c][r];
  }
}

// ---------------- RoPE cos/sin table ----------------
__global__ void rope_table_k(float* __restrict__ tab) {
  int i = blockIdx.x * 256 + threadIdx.x;
  int s = i >> 6, d = i & 63;
  float inv = expf(-(float)d * (9.210340371976184f / 64.0f));
  float ang = (float)s * inv;
  tab[s * 128 + d] = cosf(ang);
  tab[s * 128 + 64 + d] = sinf(ang);
}

// ---------------- relative bias ----------------
__global__ void build_bias_k(const void* __restrict__ table, float* __restrict__ bias,
                             const int* __restrict__ flag) {
  int i = blockIdx.x * 256 + threadIdx.x;
  int h = i >> 11, dist = i & 2047;
  int bucket;
  if (dist < 16) bucket = dist;
  else {
    int lb = (int)(logf((float)dist * 0.0625f) / 2.0794415f * 16.0f) + 16;
    bucket = lb < 31 ? lb : 31;
  }
  int ti = bucket * NHEAD + h;
  float tv = (*flag) ? ((const float*)table)[ti] : b2f(((const u16*)table)[ti]);
  bias[h * 2048 + dist] = tv;
}

// ---------------- GEMM (m97 structure): C = A[M][K] * B[N][K]^T ----------------
template <bool F32OUT>
__global__ __launch_bounds__(256) void gemm_bt(const u16* __restrict__ A, const u16* __restrict__ B,
                                               void* __restrict__ Cv, int M, int N, int K) {
  __shared__ __align__(16) u16 As[128 * 32];  // unpadded: required by global_load_lds;
  __shared__ __align__(16) u16 Bs[128 * 32];  // [128][32] rows are at the b128 bank floor
  int tid = threadIdx.x;
  int lane = tid & 63, wv = tid >> 6;
  int wm = wv & 1, wn = wv >> 1;
  int lane16 = lane & 15, quad = lane >> 4;
  int m0 = blockIdx.y * 128, n0 = blockIdx.x * 128;

  // staging: wave wv instr t in {0,1}: 16 rows (wv*32+t*16), lane -> row l>>2, chunk l&3
  const u16* pA = A + (size_t)(m0 + wv * 32 + (lane >> 2)) * K + (lane & 3) * 8;
  const u16* pB = B + (size_t)(n0 + wv * 32 + (lane >> 2)) * K + (lane & 3) * 8;
  u16* lA = As + wv * 1024;  // 2 groups x 512 u16
  u16* lB = Bs + wv * 1024;

  f32x4 zero4 = {0.f, 0.f, 0.f, 0.f};
  f32x4 acc[4][4];
#pragma unroll
  for (int i = 0; i < 4; ++i)
#pragma unroll
    for (int j = 0; j < 4; ++j) acc[i][j] = zero4;

  int nk = K >> 5;
  for (int kt = 0; kt < nk; ++kt) {
    __syncthreads();
    gl_lds16(pA, lA);
    gl_lds16(pA + (size_t)16 * K, lA + 512);
    gl_lds16(pB, lB);
    gl_lds16(pB + (size_t)16 * K, lB + 512);
    pA += 32; pB += 32;
    __syncthreads();  // vmcnt(0) drain -> tiles visible
    bf16x8 af[4], bfr[4];
#pragma unroll
    for (int i = 0; i < 4; ++i)
      af[i] = *(const bf16x8*)&As[(wm * 64 + i * 16 + lane16) * 32 + quad * 8];
#pragma unroll
    for (int j = 0; j < 4; ++j)
      bfr[j] = *(const bf16x8*)&Bs[(wn * 64 + j * 16 + lane16) * 32 + quad * 8];
#pragma unroll
    for (int i = 0; i < 4; ++i)
#pragma unroll
      for (int j = 0; j < 4; ++j)
        acc[i][j] = __builtin_amdgcn_mfma_f32_16x16x32_bf16(af[i], bfr[j], acc[i][j], 0, 0, 0);
  }
#pragma unroll
  for (int i = 0; i < 4; ++i)
#pragma unroll
    for (int j = 0; j < 4; ++j)
#pragma unroll
      for (int r = 0; r < 4; ++r) {
        int row = m0 + wm * 64 + i * 16 + quad * 4 + r;
        int col = n0 + wn * 64 + j * 16 + lane16;
        if (F32OUT)
          ((float*)Cv)[(size_t)row * N + col] = acc[i][j][r];
        else
          ((u16*)Cv)[(size_t)row * N + col] = f2b(acc[i][j][r]);
      }
}

// ---------------- reorg: qkv[B,S,6144] -> q,k [bh,S,D] (roped), vT [bh,D,S] ----------------
__global__ __launch_bounds__(256) void reorg_k(const u16* __restrict__ qkv, const float* __restrict__ tab,
                                               u16* __restrict__ q, u16* __restrict__ k,
                                               u16* __restrict__ vT) {
  __shared__ float vt[64][129];
  int tid = threadIdx.x;
  int st = blockIdx.x, bh = blockIdx.y;
  int b = bh >> 4, h = bh & 15;
  int s0 = st * 64;
  const u16* base = qkv + (size_t)(b * S_LEN + s0) * QKV_N + h * HD;
  u16* qo = q + ((size_t)bh * S_LEN + s0) * HD;
  u16* ko = k + ((size_t)bh * S_LEN + s0) * HD;
#pragma unroll
  for (int p = 0; p < 16; ++p) {
    int e = p * 256 + tid;
    int sl = e >> 6, d = e & 63;
    float c = tab[(s0 + sl) * 128 + d];
    float sn = tab[(s0 + sl) * 128 + 64 + d];
    const u16* rowp = base + (size_t)sl * QKV_N;
    float q1 = b2f(rowp[d]), q2 = b2f(rowp[d + 64]);
    qo[sl * HD + d] = f2b(q1 * c - q2 * sn);
    qo[sl * HD + d + 64] = f2b(q2 * c + q1 * sn);
    float k1 = b2f(rowp[2048 + d]), k2 = b2f(rowp[2048 + d + 64]);
    ko[sl * HD + d] = f2b(k1 * c - k2 * sn);
    ko[sl * HD + d + 64] = f2b(k2 * c + k1 * sn);
  }
#pragma unroll
  for (int p = 0; p < 32; ++p) {
    int e = p * 256 + tid;
    int sl = e >> 7, d = e & 127;
    vt[sl][d] = b2f(base[(size_t)sl * QKV_N + 4096 + d]);
  }
  __syncthreads();
  u16* vo = vT + (size_t)bh * HD * S_LEN;
#pragma unroll
  for (int p = 0; p < 32; ++p) {
    int e = p * 256 + tid;
    int d = e >> 6, sl = e & 63;
    vo[(size_t)d * S_LEN + s0 + sl] = f2b(vt[sl][d]);
  }
}

// ---------------- flash attention, diagonal-paired q-tiles ----------------
// grid (16, 32): block p handles q-tiles p and 31-p => uniform 33 k-iters/block.
// K/V staged via global_load_lds into unpadded LDS with XOR chunk swizzle
// (chunk' = chunk ^ (row&7), 16B granularity) -> frag reads at b128 bank floor.
__global__ __launch_bounds__(256) void attn_k(const u16* __restrict__ q, const u16* __restrict__ k,
                                              const u16* __restrict__ vT, const float* __restrict__ bias,
                                              u16* __restrict__ ctx) {
  __shared__ __align__(16) u16 Ks[64 * 128];    // 16 KB, swizzled
  __shared__ __align__(16) u16 VTs[128 * 64];   // 16 KB, swizzled
  __shared__ __align__(16) u16 QP[64 * 128];    // 16 KB: Q stage, then per-wave P [16][72]
  __shared__ float bias_s[128];
  int tid = threadIdx.x;
  int lane = tid & 63, wq = tid >> 6;
  int lane16 = lane & 15, quad = lane >> 4;
  int r7 = lane16 & 7;
  int bh = blockIdx.y;
  int b = bh >> 4, h = bh & 15;
  const u16* kg = k + (size_t)bh * S_LEN * HD;
  const u16* vg = vT + (size_t)bh * HD * S_LEN;
  const float* biasr = bias + h * 2048;
  const float scale = 0.08838834764831845f;  // 1/sqrt(128)
  f32x4 zero4 = {0.f, 0.f, 0.f, 0.f};

  // staging lane roles
  int rl4 = lane >> 4, pk = lane & 15;   // K: 4 rows x 16 chunk-slots per instr
  int rl8 = lane >> 3, pv = lane & 7;    // V: 8 rows x 8 chunk-slots per instr
  u16* Pw = QP + wq * 1152;              // per-wave P [16][72] (padded; per-wave only)

  for (int half = 0; half < 2; ++half) {
    int qt = half ? (31 - blockIdx.x) : blockIdx.x;
    int q0 = qt * 64;
    const u16* qg = q + ((size_t)bh * S_LEN + q0) * HD;

    __syncthreads();  // protect QP reuse across halves
    {  // stage Q tile 64x128 (regular stores; once per half)
      int r = tid >> 4, c = (tid & 15) * 8;
#pragma unroll
      for (int p = 0; p < 4; ++p)
        *(u16x8*)&QP[(r + p * 16) * 128 + c] = *(const u16x8*)&qg[(size_t)(r + p * 16) * HD + c];
    }
    __syncthreads();
    bf16x8 qf[4];
#pragma unroll
    for (int kd = 0; kd < 4; ++kd)
      qf[kd] = *(const bf16x8*)&QP[(wq * 16 + lane16) * 128 + kd * 32 + quad * 8];
    __syncthreads();  // Q reads done before P writes reuse QP

    float m_i[4], l_i[4];
    f32x4 o[8];
#pragma unroll
    for (int r = 0; r < 4; ++r) { m_i[r] = -1e30f; l_i[r] = 0.f; }
#pragma unroll
    for (int dt = 0; dt < 8; ++dt) o[dt] = zero4;

    for (int kt = 0; kt <= qt; ++kt) {
      int k0 = kt * 64;
      if (kt) __syncthreads();  // prior iter's reads done before overwrite
      // async stage K (64x128) and V^T (128x64), swizzled
#pragma unroll
      for (int t = 0; t < 4; ++t) {
        int g = wq * 4 + t;
        int rowk = g * 4 + rl4;
        int ck = (pk & 8) | ((pk & 7) ^ (rowk & 7));
        gl_lds16(kg + (size_t)(k0 + rowk) * HD + ck * 8, Ks + g * 512);
        int rowv = g * 8 + rl8;
        int cv = pv ^ (rowv & 7);
        gl_lds16(vg + (size_t)rowv * S_LEN + k0 + cv * 8, VTs + g * 512);
      }
      if (tid < 128) {
        int dist = q0 - k0 + tid - 64;
        bias_s[tid] = (dist >= 0) ? biasr[dist] : 0.f;
      }
      __syncthreads();  // drain vmcnt -> K/V visible

      // S = Q K^T
      f32x4 sc[4];
#pragma unroll
      for (int j = 0; j < 4; ++j) sc[j] = zero4;
#pragma unroll
      for (int kd = 0; kd < 4; ++kd)
#pragma unroll
        for (int j = 0; j < 4; ++j) {
          int cd = kd * 4 + quad;
          int pos = (cd & 8) | ((cd & 7) ^ r7);
          bf16x8 kf = *(const bf16x8*)&Ks[(j * 16 + lane16) * 128 + pos * 8];
          sc[j] = __builtin_amdgcn_mfma_f32_16x16x32_bf16(qf[kd], kf, sc[j], 0, 0, 0);
        }

      // scale + bias + causal mask
      int qrel = wq * 16 + quad * 4;
#pragma unroll
      for (int j = 0; j < 4; ++j) {
        int krel = j * 16 + lane16;
#pragma unroll
        for (int r = 0; r < 4; ++r) {
          bool valid = (q0 + qrel + r) >= (k0 + krel);
          float sv = sc[j][r] * scale + bias_s[64 + (qrel + r) - krel];
          sc[j][r] = valid ? sv : -1e30f;
        }
      }
      // online softmax
      float mx[4];
#pragma unroll
      for (int r = 0; r < 4; ++r)
        mx[r] = fmaxf(fmaxf(sc[0][r], sc[1][r]), fmaxf(sc[2][r], sc[3][r]));
#pragma unroll
      for (int xm = 1; xm < 16; xm <<= 1)
#pragma unroll
        for (int r = 0; r < 4; ++r) mx[r] = fmaxf(mx[r], __shfl_xor(mx[r], xm));
      float alpha[4];
#pragma unroll
      for (int r = 0; r < 4; ++r) {
        float mn = fmaxf(m_i[r], mx[r]);
        alpha[r] = __expf(m_i[r] - mn);
        m_i[r] = mn;
      }
#pragma unroll
      for (int j = 0; j < 4; ++j)
#pragma unroll
        for (int r = 0; r < 4; ++r) sc[j][r] = __expf(sc[j][r] - m_i[r]);
      float rs[4];
#pragma unroll
      for (int r = 0; r < 4; ++r) rs[r] = (sc[0][r] + sc[1][r]) + (sc[2][r] + sc[3][r]);
#pragma unroll
      for (int xm = 1; xm < 16; xm <<= 1)
#pragma unroll
        for (int r = 0; r < 4; ++r) rs[r] += __shfl_xor(rs[r], xm);
#pragma unroll
      for (int r = 0; r < 4; ++r) l_i[r] = l_i[r] * alpha[r] + rs[r];
#pragma unroll
      for (int dt = 0; dt < 8; ++dt)
#pragma unroll
        for (int r = 0; r < 4; ++r) o[dt][r] *= alpha[r];

      // P: C layout -> A layout via per-wave LDS region (no cross-wave dep:
      // __threadfence_block orders the DS write->read within the wave)
#pragma unroll
      for (int j = 0; j < 4; ++j)
#pragma unroll
        for (int r = 0; r < 4; ++r)
          Pw[(quad * 4 + r) * 72 + j * 16 + lane16] = f2b(sc[j][r]);
      __threadfence_block();

      // O += P V
#pragma unroll
      for (int ks = 0; ks < 2; ++ks) {
        bf16x8 pf = *(const bf16x8*)&Pw[lane16 * 72 + ks * 32 + quad * 8];
#pragma unroll
        for (int dt = 0; dt < 8; ++dt) {
          int cdv = ks * 4 + quad;
          int posv = cdv ^ r7;
          bf16x8 vf = *(const bf16x8*)&VTs[(dt * 16 + lane16) * 64 + posv * 8];
          o[dt] = __builtin_amdgcn_mfma_f32_16x16x32_bf16(pf, vf, o[dt], 0, 0, 0);
        }
      }
    }
    // epilogue
#pragma unroll
    for (int r = 0; r < 4; ++r) {
      float invl = 1.0f / l_i[r];
      int srow = q0 + wq * 16 + quad * 4 + r;
      u16* orow = ctx + ((size_t)b * S_LEN + srow) * HID + h * HD;
#pragma unroll
      for (int dt = 0; dt < 8; ++dt)
        orow[dt * 16 + lane16] = f2b(o[dt][r] * invl);
    }
  }
}

extern "C" void kernel_launch(void* const* d_in, const int* in_sizes, int n_in,
                              void* d_out, int out_size, void* d_ws, size_t ws_size,
                              hipStream_t stream) {
  const void* x       = d_in[0];
  const void* qkv_w   = d_in[1];
  const void* dense_w = d_in[2];
  const void* rtable  = d_in[3];
  char* ws = (char*)d_ws;

  int*   flag  = (int*)(ws);
  float* bias  = (float*)(ws + 256);
  float* tab   = (float*)(ws + 131328);
  u16*   wdT   = (u16*)(ws + 1179904);
  u16*   vT    = (u16*)(ws + 9568512);
  u16*   x_bf  = (u16*)(ws + 26345728);
  u16*   qA    = x_bf;
  u16*   wqkvT = (u16*)(ws + 43122944);
  u16*   kA    = wqkvT;
  u16*   qkv   = (u16*)(ws + 68288768);
  u16*   ctx   = qkv;

  detect_dtype_k<<<1, 256, 0, stream>>>(x, flag);
  convert_any_k<<<8192, 256, 0, stream>>>(x, x_bf, flag);
  transpose_any<<<dim3(96, 32), 256, 0, stream>>>(qkv_w, wqkvT, 2048, 6144, flag);
  transpose_any<<<dim3(32, 32), 256, 0, stream>>>(dense_w, wdT, 2048, 2048, flag);
  rope_table_k<<<512, 256, 0, stream>>>(tab);
  build_bias_k<<<128, 256, 0, stream>>>(rtable, bias, flag);
  gemm_bt<false><<<dim3(48, 32), 256, 0, stream>>>(x_bf, wqkvT, qkv, 4096, 6144, 2048);
  reorg_k<<<dim3(32, 32), 256, 0, stream>>>(qkv, tab, qA, kA, vT);
  attn_k<<<dim3(16, 32), 256, 0, stream>>>(qA, kA, vT, bias, ctx);
  gemm_bt<true><<<dim3(16, 32), 256, 0, stream>>>(ctx, wdT, d_out, 4096, 2048, 2048);
}